// Round 13
// baseline (534.153 us; speedup 1.0000x reference)
//
#include <hip/hip_runtime.h>
#include <hip/hip_bf16.h>
#include <stdint.h>

// WeightOnlyInt8Linear: out[m][n] = (sum_k x[m][k]*wq[n][k]) * scale[n] + bias[n]
// M = B*S = 8192, K = 4096, N = 11008.
// Harness dtypes (verified round 3): x f32, wq int32, scale/bias f32, out f32.
//
// Round 13: mfma_i32_32x32x32_i8 (4404 vs 3944 TOPS µbench) with BK=256.
// R7's 32x32 failure was bank conflicts (128B rows = 8 slots < 32 rows);
// 256B rows = 16 slots -> XOR-16 swizzle is bijective per 16-lane quarter
// -> conflict-free. 128x128 tile, 8 waves (2m x 4n, 64x32/wave), single
// 64KB buffer -> 2 blocks/CU (16 waves/CU), m97-style loop (compiler waits).
// A and B share the same lane->(row,k) map so any HW k-permutation cancels.

#define M_DIM 8192
#define N_DIM 11008
#define K_DIM 4096

// fused-fallback geometry (only used if ws too small)
#define BM 128
#define BN 128
#define BK 32

// i8 GEMM geometry
#define BM3 128
#define BN3 128
#define BK3 256
#define NT3 (K_DIM / BK3)   // 16

#define XSCALE (6.0f / 127.0f)
#define XQSCALE (127.0f / 6.0f)

typedef __attribute__((ext_vector_type(4)))  float f32x4;
typedef __attribute__((ext_vector_type(4)))  int   i32x4;
typedef __attribute__((ext_vector_type(16))) int   i32x16;

__device__ __forceinline__ uint2 pack4_bf16(float f0, float f1, float f2, float f3) {
    union { ushort u[4]; uint2 v; } pk;
    pk.u[0] = __bfloat16_as_ushort(__float2bfloat16(f0));
    pk.u[1] = __bfloat16_as_ushort(__float2bfloat16(f1));
    pk.u[2] = __bfloat16_as_ushort(__float2bfloat16(f2));
    pk.u[3] = __bfloat16_as_ushort(__float2bfloat16(f3));
    return pk.v;
}

__device__ __forceinline__ void gload_lds16(const void* g, void* s) {
    __builtin_amdgcn_global_load_lds(
        (const __attribute__((address_space(1))) void*)g,
        (__attribute__((address_space(3))) void*)s, 16, 0, 0);
}

#define RD16I(OFF) (*(const i32x4*)(lds + (OFF)))

// ---------------- pre-pass: f32 -> int8 (scale 127/6, RNE, clamp) ----------
__device__ __forceinline__ uint32_t q4(float a, float b, float c, float d) {
    int i0 = __float2int_rn(fminf(fmaxf(a * XQSCALE, -127.f), 127.f));
    int i1 = __float2int_rn(fminf(fmaxf(b * XQSCALE, -127.f), 127.f));
    int i2 = __float2int_rn(fminf(fmaxf(c * XQSCALE, -127.f), 127.f));
    int i3 = __float2int_rn(fminf(fmaxf(d * XQSCALE, -127.f), 127.f));
    return ((uint32_t)i0 & 0xFF) | (((uint32_t)i1 & 0xFF) << 8) |
           (((uint32_t)i2 & 0xFF) << 16) | ((uint32_t)i3 << 24);
}

extern "C" __global__ __launch_bounds__(256)
void cvt_x_i8(const float* __restrict__ in, uint32_t* __restrict__ out, int n16) {
    int idx = blockIdx.x * blockDim.x + threadIdx.x;
    const int stride = gridDim.x * blockDim.x;
    for (; idx < n16; idx += stride) {
        const size_t base = (size_t)idx * 16;
        f32x4 a = *(const f32x4*)(in + base);
        f32x4 b = *(const f32x4*)(in + base + 4);
        f32x4 c = *(const f32x4*)(in + base + 8);
        f32x4 d = *(const f32x4*)(in + base + 12);
        uint4 o;
        o.x = q4(a.x, a.y, a.z, a.w);
        o.y = q4(b.x, b.y, b.z, b.w);
        o.z = q4(c.x, c.y, c.z, c.w);
        o.w = q4(d.x, d.y, d.z, d.w);
        *(uint4*)(out + (size_t)idx * 4) = o;
    }
}

extern "C" __global__ __launch_bounds__(256)
void cvt_w_i8(const int* __restrict__ in, uint32_t* __restrict__ out, int n16) {
    int idx = blockIdx.x * blockDim.x + threadIdx.x;
    const int stride = gridDim.x * blockDim.x;
    for (; idx < n16; idx += stride) {
        const size_t base = (size_t)idx * 16;
        i32x4 a = *(const i32x4*)(in + base);
        i32x4 b = *(const i32x4*)(in + base + 4);
        i32x4 c = *(const i32x4*)(in + base + 8);
        i32x4 d = *(const i32x4*)(in + base + 12);
        uint4 o;
        o.x = ((uint32_t)a.x & 0xFF) | (((uint32_t)a.y & 0xFF) << 8) |
              (((uint32_t)a.z & 0xFF) << 16) | ((uint32_t)a.w << 24);
        o.y = ((uint32_t)b.x & 0xFF) | (((uint32_t)b.y & 0xFF) << 8) |
              (((uint32_t)b.z & 0xFF) << 16) | ((uint32_t)b.w << 24);
        o.z = ((uint32_t)c.x & 0xFF) | (((uint32_t)c.y & 0xFF) << 8) |
              (((uint32_t)c.z & 0xFF) << 16) | ((uint32_t)c.w << 24);
        o.w = ((uint32_t)d.x & 0xFF) | (((uint32_t)d.y & 0xFF) << 8) |
              (((uint32_t)d.z & 0xFF) << 16) | ((uint32_t)d.w << 24);
        *(uint4*)(out + (size_t)idx * 4) = o;
    }
}

// ------- main GEMM: 128x128, BK=256, 8 waves, 32x32x32 i8, 2 blocks/CU -----
extern "C" __global__ __launch_bounds__(512, 4)
void wq8_gemm_i8w(const char* __restrict__ Xq,   // int8 [M][K]
                  const char* __restrict__ Wq8,  // int8 [N][K]
                  const float* __restrict__ Sc,
                  const float* __restrict__ Bi,
                  float* __restrict__ Out)
{
    // LDS single buffer: A[128][256B] at 0, B[128][256B] at 32768. 64 KB.
    __shared__ __align__(16) char lds[65536];

    const int tid = (int)threadIdx.x;
    const int l   = tid & 63;
    const int w   = tid >> 6;      // wave 0..7
    const int wr  = w >> 2;        // 0..1  (M-half: 64 rows)
    const int wc  = w & 3;         // 0..3  (N-quarter: 32 cols)

    // XCD swizzle (nwg = 5504 = 8*688) + GROUP_M=8 supertile map.
    const int nwg  = (M_DIM / BM3) * (N_DIM / BN3);   // 64*86 = 5504
    const int bid  = (int)blockIdx.x;
    const int wgid = (bid & 7) * (nwg >> 3) + (bid >> 3);
    const int grp  = wgid / 688;          // 0..7
    const int rr   = wgid % 688;
    const int tm   = grp * 8 + (rr & 7);  // 0..63
    const int tn   = rr >> 3;             // 0..85
    const int gM   = tm * BM3;
    const int gN   = tn * BN3;

    const char* aBase = Xq  + (size_t)gM * K_DIM;
    const char* bBase = Wq8 + (size_t)gN * K_DIM;

    // Reader swizzle (256B rows, 16 slots): logical col c of row r lives at
    // byte r*256 + (c ^ ((r&15)<<4)). 32x32 frag read: rows base+(l&31)
    // (base mult of 32 -> r&15 == l&15), col = ks*32 + (l>>5)*16.
    // Per 16-lane quarter: 16 distinct rows -> 16 distinct slots: 0-conflict.
    const int rx   = (l & 15) << 4;
    const int kcol = (l >> 5) << 4;                      // 0 or 16
    const int arow = (wr * 64 + (l & 31)) * 256;         // + mi*8192
    const int brow = 32768 + (wc * 32 + (l & 31)) * 256;

    // Stage: one gload_lds = 1 KB = 4 rows (lane l -> row rb+(l>>4), slot l&15).
    // Inverse-swizzled source col so LDS content is linear-with-XOR (rule 21):
    // global slot = (l&15) ^ ((rb + (l>>4)) & 15); rb&15 in {0,4,8,12}.
    auto STAGE = [&](const char* base, int ldsOfs, int rb, int kofs) {
        const int rowSub = (rb & 15) + (l >> 4);
        const int srcCol = ((l & 15) ^ rowSub) << 4;
        gload_lds16(base + (size_t)(rb + (l >> 4)) * K_DIM + kofs + srcCol,
                    lds + ldsOfs + rb * 256);
    };

    i32x16 acc[2];
    acc[0] = (i32x16)0;
    acc[1] = (i32x16)0;

    for (int t = 0; t < NT3; ++t) {
        const int kofs = t * BK3;

        // Stage full A and B tiles: 32 chunks of 4 rows each, 4 A + 4 B per wave.
        #pragma unroll
        for (int i = 0; i < 4; ++i) {
            const int rb = (i * 8 + w) * 4;               // wave-uniform
            STAGE(aBase, 0,     rb, kofs);
            STAGE(bBase, 32768, rb, kofs);
        }

        __syncthreads();   // compiler drains vmcnt before s_barrier

        __builtin_amdgcn_s_setprio(1);
        #pragma unroll
        for (int ks = 0; ks < 8; ++ks) {
            const int c = ((ks * 32 + kcol) ^ rx);
            i32x4 a0 = RD16I(arow + c);
            i32x4 a1 = RD16I(arow + 8192 + c);
            i32x4 bf = RD16I(brow + c);
            acc[0] = __builtin_amdgcn_mfma_i32_32x32x32_i8(a0, bf, acc[0], 0, 0, 0);
            acc[1] = __builtin_amdgcn_mfma_i32_32x32x32_i8(a1, bf, acc[1], 0, 0, 0);
        }
        __builtin_amdgcn_s_setprio(0);

        __syncthreads();   // all reads done before next overwrite
    }

    // ---- Epilogue: dequant + scale + bias, f32 store.
    // C/D 32x32 (m74/m101, dtype-independent): col = lane&31,
    // row = (reg&3) + 8*(reg>>2) + 4*(lane>>5). (Verified in-family by R7.)
    const int lc = l & 31;
    const int lh = (l >> 5) * 4;
    const int gn = gN + wc * 32 + lc;
    const float sc = Sc[gn] * XSCALE;
    const float bi = Bi[gn];
    #pragma unroll
    for (int mi = 0; mi < 2; ++mi) {
        const int m0 = gM + wr * 64 + mi * 32 + lh;
        #pragma unroll
        for (int reg = 0; reg < 16; ++reg) {
            const int gm = m0 + (reg & 3) + 8 * (reg >> 2);
            Out[(size_t)gm * N_DIM + gn] = (float)acc[mi][reg] * sc + bi;
        }
    }
}

// ---------------- fallback: fused 128x128 bf16 (round-2, proven) -----------
extern "C" __global__ __launch_bounds__(256)
void wq8_gemm_fused(const float* __restrict__ X,
                    const int* __restrict__ Wq,
                    const float* __restrict__ Sc,
                    const float* __restrict__ Bi,
                    float* __restrict__ Out)
{
    __shared__ __hip_bfloat16 As[BM][BK];
    __shared__ __hip_bfloat16 Bs[BN][BK];

    const int tid = threadIdx.x;
    const int w   = tid >> 6;
    const int l   = tid & 63;
    const int wr  = w >> 1;
    const int wc  = w & 1;
    const int fr  = l & 15;
    const int fq  = l >> 4;

    const int ntn  = N_DIM / BN;
    const int nwg  = (M_DIM / BM) * ntn;
    const int bid  = (int)blockIdx.x;
    const int wgid = (bid & 7) * (nwg >> 3) + (bid >> 3);
    const int g    = wgid / (8 * ntn);
    const int rr   = wgid % (8 * ntn);
    const int tm   = g * 8 + (rr & 7);
    const int tn   = rr >> 3;

    const int srow = tid >> 3;
    const int scol = (tid & 7) * 4;
    const float* a_g = X  + (size_t)(tm * BM + srow) * K_DIM + scol;
    const int*   b_g = Wq + (size_t)(tn * BN + srow) * K_DIM + scol;

    f32x4 acc[4][4];
    #pragma unroll
    for (int m = 0; m < 4; ++m)
        #pragma unroll
        for (int n = 0; n < 4; ++n)
            acc[m][n] = (f32x4)0.0f;

    typedef __attribute__((ext_vector_type(8))) short bf16x8_t;
    for (int kt = 0; kt < K_DIM / BK; ++kt) {
        const int kofs = kt * BK;
        f32x4 xa[4];
        i32x4 wv[4];
        #pragma unroll
        for (int q = 0; q < 4; ++q)
            xa[q] = *(const f32x4*)(a_g + (size_t)q * 32 * K_DIM + kofs);
        #pragma unroll
        for (int q = 0; q < 4; ++q)
            wv[q] = *(const i32x4*)(b_g + (size_t)q * 32 * K_DIM + kofs);

        uint2 ap[4], bp[4];
        #pragma unroll
        for (int q = 0; q < 4; ++q) {
            ap[q] = pack4_bf16(xa[q].x, xa[q].y, xa[q].z, xa[q].w);
            bp[q] = pack4_bf16((float)wv[q].x, (float)wv[q].y,
                               (float)wv[q].z, (float)wv[q].w);
        }

        __syncthreads();
        #pragma unroll
        for (int q = 0; q < 4; ++q) {
            *(uint2*)(&As[q * 32 + srow][scol]) = ap[q];
            *(uint2*)(&Bs[q * 32 + srow][scol]) = bp[q];
        }
        __syncthreads();

        bf16x8_t af[4], bfr[4];
        #pragma unroll
        for (int m = 0; m < 4; ++m)
            af[m] = *(const bf16x8_t*)(&As[wr * 64 + m * 16 + fr][fq * 8]);
        #pragma unroll
        for (int n = 0; n < 4; ++n)
            bfr[n] = *(const bf16x8_t*)(&Bs[wc * 64 + n * 16 + fr][fq * 8]);
        #pragma unroll
        for (int m = 0; m < 4; ++m)
            #pragma unroll
            for (int n = 0; n < 4; ++n)
                acc[m][n] = __builtin_amdgcn_mfma_f32_16x16x32_bf16(
                    af[m], bfr[n], acc[m][n], 0, 0, 0);
    }

    const int n_base = tn * BN + wc * 64;
    const int m_base = tm * BM + wr * 64;
    #pragma unroll
    for (int n = 0; n < 4; ++n) {
        const int gn = n_base + n * 16 + fr;
        const float sc = Sc[gn];
        const float bi = Bi[gn];
        #pragma unroll
        for (int m = 0; m < 4; ++m) {
            const int gm0 = m_base + m * 16 + fq * 4;
            #pragma unroll
            for (int j = 0; j < 4; ++j)
                Out[(size_t)(gm0 + j) * N_DIM + gn] = acc[m][n][j] * sc + bi;
        }
    }
}

extern "C" void kernel_launch(void* const* d_in, const int* in_sizes, int n_in,
                              void* d_out, int out_size, void* d_ws, size_t ws_size,
                              hipStream_t stream) {
    const float* X  = (const float*)d_in[0];
    const int*   Wq = (const int*)d_in[1];
    const float* Sc = (const float*)d_in[2];
    const float* Bi = (const float*)d_in[3];
    float*      Out = (float*)d_out;

    const size_t nX = (size_t)M_DIM * K_DIM;     // 33,554,432
    const size_t nW = (size_t)N_DIM * K_DIM;     // 45,088,768
    const size_t ws_needed = nX + nW;            // 78.6 MB (int8)

    if (ws_size >= ws_needed) {
        char* Xq  = (char*)d_ws;
        char* Wq8 = Xq + nX;
        cvt_x_i8<<<2048, 256, 0, stream>>>(X, (uint32_t*)Xq, (int)(nX / 16));
        cvt_w_i8<<<2048, 256, 0, stream>>>(Wq, (uint32_t*)Wq8, (int)(nW / 16));
        dim3 grid3((M_DIM / BM3) * (N_DIM / BN3));   // 5504
        wq8_gemm_i8w<<<grid3, 512, 0, stream>>>(Xq, Wq8, Sc, Bi, Out);
    } else {
        dim3 grid((M_DIM / BM) * (N_DIM / BN));      // 5504
        wq8_gemm_fused<<<grid, 256, 0, stream>>>(X, Wq, Sc, Bi, Out);
    }
}

// Round 14
// 481.050 us; speedup vs baseline: 1.1104x; 1.1104x over previous
//
#include <hip/hip_runtime.h>
#include <hip/hip_bf16.h>
#include <stdint.h>

// WeightOnlyInt8Linear: out[m][n] = (sum_k x[m][k]*wq[n][k]) * scale[n] + bias[n]
// M = B*S = 8192, K = 4096, N = 11008.
// Harness dtypes (verified round 3): x f32, wq int32, scale/bias f32, out f32.
//
// Round 14: REVERT to Round 8 (best measured: 483.7 us total, GEMM ~420 us).
// R6-R13 tested 7 structural variants (read placement, MFMA shape 16x16/32x32,
// occupancy 1/2/3 blocks per CU, barrier density, drain elimination) — all
// null or negative vs this configuration. Keeper:
//   pre-pass: X f32->i8 (tensor scale 6/127, RNE), W i32->i8 (exact pack);
//   GEMM: 256x256 tile, BK=128 i8, 8 waves, 128KB LDS double-buffer, 4-phase
//   schedule w/ counted vmcnt (never 0 in steady state), XOR-swizzled LDS
//   (0 bank conflicts), mfma_i32_16x16x64_i8, f32 dequant epilogue.

#define M_DIM 8192
#define N_DIM 11008
#define K_DIM 4096

// 128x128 fused fallback geometry (only used if ws too small)
#define BM 128
#define BN 128
#define BK 32

// 256x256 8-phase geometry (int8: BK2 in elements = bytes)
#define BM2 256
#define BN2 256
#define BK2 128
#define NT2 (K_DIM / BK2)   // 32

#define XSCALE (6.0f / 127.0f)
#define XQSCALE (127.0f / 6.0f)

typedef __attribute__((ext_vector_type(4)))  float f32x4;
typedef __attribute__((ext_vector_type(8)))  short bf16x8;
typedef __attribute__((ext_vector_type(4)))  int   i32x4;

__device__ __forceinline__ uint2 pack4_bf16(float f0, float f1, float f2, float f3) {
    union { ushort u[4]; uint2 v; } pk;
    pk.u[0] = __bfloat16_as_ushort(__float2bfloat16(f0));
    pk.u[1] = __bfloat16_as_ushort(__float2bfloat16(f1));
    pk.u[2] = __bfloat16_as_ushort(__float2bfloat16(f2));
    pk.u[3] = __bfloat16_as_ushort(__float2bfloat16(f3));
    return pk.v;
}

__device__ __forceinline__ void gload_lds16(const void* g, void* s) {
    __builtin_amdgcn_global_load_lds(
        (const __attribute__((address_space(1))) void*)g,
        (__attribute__((address_space(3))) void*)s, 16, 0, 0);
}

#define SCHED0()  __builtin_amdgcn_sched_barrier(0)
#define BAR() do { __builtin_amdgcn_s_barrier(); \
                   asm volatile("" ::: "memory"); } while (0)
#define LGKM0() do { asm volatile("s_waitcnt lgkmcnt(0)" ::: "memory"); \
                     __builtin_amdgcn_sched_barrier(0); } while (0)
#define VMC(N)  do { asm volatile("s_waitcnt vmcnt(" #N ")" ::: "memory"); } while (0)

#define RD16I(OFF) (*(const i32x4*)(lds + (OFF)))

// 16-MFMA i8 quadrant cluster, setprio-wrapped (T5). MH/NH literals.
#define QUADI8(MH, NH, A, B)                                                   \
  do {                                                                         \
    __builtin_amdgcn_s_setprio(1);                                             \
    _Pragma("unroll")                                                          \
    for (int mi = 0; mi < 4; ++mi) {                                           \
      _Pragma("unroll")                                                        \
      for (int ni = 0; ni < 2; ++ni) {                                         \
        acc[(MH)*4+mi][(NH)*2+ni] = __builtin_amdgcn_mfma_i32_16x16x64_i8(     \
            (A)[mi][0], (B)[ni][0], acc[(MH)*4+mi][(NH)*2+ni], 0, 0, 0);       \
        acc[(MH)*4+mi][(NH)*2+ni] = __builtin_amdgcn_mfma_i32_16x16x64_i8(     \
            (A)[mi][1], (B)[ni][1], acc[(MH)*4+mi][(NH)*2+ni], 0, 0, 0);       \
      }                                                                        \
    }                                                                          \
    __builtin_amdgcn_s_setprio(0);                                             \
  } while (0)

// ---------------- pre-pass: f32 -> int8 (scale 127/6, RNE, clamp) ----------
__device__ __forceinline__ uint32_t q4(float a, float b, float c, float d) {
    int i0 = __float2int_rn(fminf(fmaxf(a * XQSCALE, -127.f), 127.f));
    int i1 = __float2int_rn(fminf(fmaxf(b * XQSCALE, -127.f), 127.f));
    int i2 = __float2int_rn(fminf(fmaxf(c * XQSCALE, -127.f), 127.f));
    int i3 = __float2int_rn(fminf(fmaxf(d * XQSCALE, -127.f), 127.f));
    return ((uint32_t)i0 & 0xFF) | (((uint32_t)i1 & 0xFF) << 8) |
           (((uint32_t)i2 & 0xFF) << 16) | ((uint32_t)i3 << 24);
}

extern "C" __global__ __launch_bounds__(256)
void cvt_x_i8(const float* __restrict__ in, uint32_t* __restrict__ out, int n16) {
    int idx = blockIdx.x * blockDim.x + threadIdx.x;
    const int stride = gridDim.x * blockDim.x;
    for (; idx < n16; idx += stride) {
        const size_t base = (size_t)idx * 16;
        f32x4 a = *(const f32x4*)(in + base);
        f32x4 b = *(const f32x4*)(in + base + 4);
        f32x4 c = *(const f32x4*)(in + base + 8);
        f32x4 d = *(const f32x4*)(in + base + 12);
        uint4 o;
        o.x = q4(a.x, a.y, a.z, a.w);
        o.y = q4(b.x, b.y, b.z, b.w);
        o.z = q4(c.x, c.y, c.z, c.w);
        o.w = q4(d.x, d.y, d.z, d.w);
        *(uint4*)(out + (size_t)idx * 4) = o;
    }
}

// ---------------- pre-pass: int32 -> int8 (byte pack, exact) ---------------
extern "C" __global__ __launch_bounds__(256)
void cvt_w_i8(const int* __restrict__ in, uint32_t* __restrict__ out, int n16) {
    int idx = blockIdx.x * blockDim.x + threadIdx.x;
    const int stride = gridDim.x * blockDim.x;
    for (; idx < n16; idx += stride) {
        const size_t base = (size_t)idx * 16;
        i32x4 a = *(const i32x4*)(in + base);
        i32x4 b = *(const i32x4*)(in + base + 4);
        i32x4 c = *(const i32x4*)(in + base + 8);
        i32x4 d = *(const i32x4*)(in + base + 12);
        uint4 o;
        o.x = ((uint32_t)a.x & 0xFF) | (((uint32_t)a.y & 0xFF) << 8) |
              (((uint32_t)a.z & 0xFF) << 16) | ((uint32_t)a.w << 24);
        o.y = ((uint32_t)b.x & 0xFF) | (((uint32_t)b.y & 0xFF) << 8) |
              (((uint32_t)b.z & 0xFF) << 16) | ((uint32_t)b.w << 24);
        o.z = ((uint32_t)c.x & 0xFF) | (((uint32_t)c.y & 0xFF) << 8) |
              (((uint32_t)c.z & 0xFF) << 16) | ((uint32_t)c.w << 24);
        o.w = ((uint32_t)d.x & 0xFF) | (((uint32_t)d.y & 0xFF) << 8) |
              (((uint32_t)d.z & 0xFF) << 16) | ((uint32_t)d.w << 24);
        *(uint4*)(out + (size_t)idx * 4) = o;
    }
}

// ---------------- main GEMM: 256x256, 8-wave, 8-phase, int8 MFMA -----------
extern "C" __global__ __launch_bounds__(512, 2)
void wq8_gemm_i8(const char* __restrict__ Xq,   // int8 [M][K]
                 const char* __restrict__ Wq8,  // int8 [N][K]
                 const float* __restrict__ Sc,
                 const float* __restrict__ Bi,
                 float* __restrict__ Out)
{
    // LDS: buf b at b*65536; within buf: A[256][128B] at 0, B[256][128B] at 32768.
    __shared__ __align__(16) char lds[131072];

    const int tid = (int)threadIdx.x;
    const int l   = tid & 63;
    const int w   = tid >> 6;      // wave 0..7
    const int wr  = w >> 2;        // 0..1  (M-half)
    const int wc  = w & 3;         // 0..3  (N-quarter)
    const int fr  = l & 15;
    const int fq  = l >> 4;

    // XCD swizzle (nwg = 1376 = 8*172) + GROUP_M=8 supertile map.
    const int nwg  = (M_DIM / BM2) * (N_DIM / BN2);   // 1376
    const int bid  = (int)blockIdx.x;
    const int wgid = (bid & 7) * (nwg >> 3) + (bid >> 3);
    const int grp  = wgid / 344;          // 8 * 43
    const int rr   = wgid % 344;
    const int tm   = grp * 8 + (rr & 7);  // 0..31
    const int tn   = rr >> 3;             // 0..42
    const int gM   = tm * BM2;
    const int gN   = tn * BN2;

    // Staging: LDS written LINEARLY by gload_lds; XOR swizzle realized by
    // inverse-permuting the per-lane GLOBAL source 16B-slot (rule 21 / m173):
    // LDS slot s of row r holds logical slot s ^ (r&7).
    const int slotOfs = ((l & 7) ^ (l >> 3)) * 16;    // bytes within 128B row

    // Reader: frag(row r, kk) 16B at byte r*128 + ((kk*64 + fq*16) ^ ((r&7)<<4)).
    // r&7 == l&7 for all frag rows (bases are multiples of 16). 0-conflict.
    const int cA0  = ((l >> 4) * 16) ^ ((l & 7) << 4);
    const int cA1  = cA0 ^ 64;
    const int arow = wr * 16384 + (l & 15) * 128;          // + mi*2048
    const int brow = 32768 + (wc * 64 + (l & 15)) * 128;   // + ni*2048

    auto STAGE_A = [&](int bufb, int rowbase, int kofs) {
        const char* src = Xq + (size_t)(gM + rowbase + (tid >> 3)) * K_DIM
                             + kofs + slotOfs;
        char* dst = lds + bufb + rowbase * 128 + (w << 10);   // wave-uniform
        gload_lds16(src, dst);
    };
    auto STAGE_B = [&](int bufb, int j, int h, int kofs) {
        const int c = j * 8 + w;
        const int rowbase = (c >> 2) * 64 + h * 32 + (c & 3) * 8;
        const char* src = Wq8 + (size_t)(gN + rowbase + (l >> 3)) * K_DIM
                              + kofs + slotOfs;
        char* dst = lds + bufb + 32768 + rowbase * 128;       // wave-uniform
        gload_lds16(src, dst);
    };

    i32x4 acc[8][4];
    #pragma unroll
    for (int m = 0; m < 8; ++m)
        #pragma unroll
        for (int n = 0; n < 4; ++n)
            acc[m][n] = (i32x4)0;

    // Prologue: tile0 complete + tile1 {A-m0, B-n0} (12 loads, canonical order).
    STAGE_A(0, 0, 0);        STAGE_A(0, 128, 0);        // A-m0(0)
    STAGE_B(0, 0, 0, 0);     STAGE_B(0, 1, 0, 0);       // B-n0(0)
    STAGE_A(0, 64, 0);       STAGE_A(0, 192, 0);        // A-m1(0)
    STAGE_B(0, 0, 1, 0);     STAGE_B(0, 1, 1, 0);       // B-n1(0)
    STAGE_A(65536, 0, BK2);  STAGE_A(65536, 128, BK2);  // A-m0(1)
    STAGE_B(65536, 0, 0, BK2); STAGE_B(65536, 1, 0, BK2); // B-n0(1)
    VMC(8);                 // tile0's A-m0,B-n0 landed
    BAR(); SCHED0();

    i32x4 af[4][2], bf01[2][2], bf23[2][2];

    for (int t = 0; t < NT2; ++t) {
        const int buf  = (t & 1) << 16;
        const int nbuf = buf ^ 65536;
        const int k1   = (t + 1) * BK2;
        const int k2   = (t + 2) * BK2;
        const bool nx1 = (t + 1 < NT2);
        const bool nx2 = (t + 2 < NT2);

        // ---- phase 0: read A-mh0(t)+B-n01(t); stage A-m1(t+1); QUAD(0,0)
        #pragma unroll
        for (int mi = 0; mi < 4; ++mi) {
            af[mi][0] = RD16I(buf + arow + mi * 2048 + cA0);
            af[mi][1] = RD16I(buf + arow + mi * 2048 + cA1);
        }
        #pragma unroll
        for (int ni = 0; ni < 2; ++ni) {
            bf01[ni][0] = RD16I(buf + brow + ni * 2048 + cA0);
            bf01[ni][1] = RD16I(buf + brow + ni * 2048 + cA1);
        }
        if (nx1) { STAGE_A(nbuf, 64, k1); STAGE_A(nbuf, 192, k1); }
        BAR();
        LGKM0();
        QUADI8(0, 0, af, bf01);
        if (nx1) { VMC(6); } else { VMC(0); }
        BAR(); SCHED0();

        // ---- phase 1: read B-n23(t); stage B-n1(t+1); QUAD(0,1)
        #pragma unroll
        for (int ni = 0; ni < 2; ++ni) {
            bf23[ni][0] = RD16I(buf + brow + (2 + ni) * 2048 + cA0);
            bf23[ni][1] = RD16I(buf + brow + (2 + ni) * 2048 + cA1);
        }
        if (nx1) { STAGE_B(nbuf, 0, 1, k1); STAGE_B(nbuf, 1, 1, k1); }
        BAR();
        LGKM0();
        QUADI8(0, 1, af, bf23);
        BAR(); SCHED0();

        // ---- phase 2: read A-mh1(t); stage A-m0(t+2); QUAD(1,0)
        #pragma unroll
        for (int mi = 0; mi < 4; ++mi) {
            af[mi][0] = RD16I(buf + arow + 8192 + mi * 2048 + cA0);
            af[mi][1] = RD16I(buf + arow + 8192 + mi * 2048 + cA1);
        }
        if (nx2) { STAGE_A(buf, 0, k2); STAGE_A(buf, 128, k2); }
        BAR();
        LGKM0();
        QUADI8(1, 0, af, bf01);
        BAR(); SCHED0();

        // ---- phase 3: stage B-n0(t+2); QUAD(1,1)
        if (nx2) { STAGE_B(buf, 0, 0, k2); STAGE_B(buf, 1, 0, k2); }
        BAR();
        QUADI8(1, 1, af, bf23);
        if (nx2)      { VMC(8); }
        else if (nx1) { VMC(4); }
        BAR(); SCHED0();
    }

    // ---- Epilogue: dequant + scale + bias, f32 store.
    // C/D (dtype-independent, m121-m128): col = l&15, row = (l>>4)*4 + j.
    const int n_base = gN + wc * 64;
    const int m_base = gM + wr * 128;
    #pragma unroll
    for (int n = 0; n < 4; ++n) {
        const int gn = n_base + n * 16 + fr;
        const float sc = Sc[gn] * XSCALE;
        const float bi = Bi[gn];
        #pragma unroll
        for (int m = 0; m < 8; ++m) {
            const int gm0 = m_base + m * 16 + fq * 4;
            #pragma unroll
            for (int j = 0; j < 4; ++j)
                Out[(size_t)(gm0 + j) * N_DIM + gn] =
                    (float)acc[m][n][j] * sc + bi;
        }
    }
}

// ---------------- fallback: fused 128x128 bf16 (round-2, proven) -----------
extern "C" __global__ __launch_bounds__(256)
void wq8_gemm_fused(const float* __restrict__ X,
                    const int* __restrict__ Wq,
                    const float* __restrict__ Sc,
                    const float* __restrict__ Bi,
                    float* __restrict__ Out)
{
    __shared__ __hip_bfloat16 As[BM][BK];
    __shared__ __hip_bfloat16 Bs[BN][BK];

    const int tid = threadIdx.x;
    const int w   = tid >> 6;
    const int l   = tid & 63;
    const int wr  = w >> 1;
    const int wc  = w & 1;
    const int fr  = l & 15;
    const int fq  = l >> 4;

    const int ntn  = N_DIM / BN;
    const int nwg  = (M_DIM / BM) * ntn;
    const int bid  = (int)blockIdx.x;
    const int wgid = (bid & 7) * (nwg >> 3) + (bid >> 3);
    const int g    = wgid / (8 * ntn);
    const int rr   = wgid % (8 * ntn);
    const int tm   = g * 8 + (rr & 7);
    const int tn   = rr >> 3;

    const int srow = tid >> 3;
    const int scol = (tid & 7) * 4;
    const float* a_g = X  + (size_t)(tm * BM + srow) * K_DIM + scol;
    const int*   b_g = Wq + (size_t)(tn * BN + srow) * K_DIM + scol;

    f32x4 acc[4][4];
    #pragma unroll
    for (int m = 0; m < 4; ++m)
        #pragma unroll
        for (int n = 0; n < 4; ++n)
            acc[m][n] = (f32x4)0.0f;

    typedef __attribute__((ext_vector_type(8))) short bf16x8_t;
    for (int kt = 0; kt < K_DIM / BK; ++kt) {
        const int kofs = kt * BK;
        f32x4 xa[4];
        i32x4 wv[4];
        #pragma unroll
        for (int q = 0; q < 4; ++q)
            xa[q] = *(const f32x4*)(a_g + (size_t)q * 32 * K_DIM + kofs);
        #pragma unroll
        for (int q = 0; q < 4; ++q)
            wv[q] = *(const i32x4*)(b_g + (size_t)q * 32 * K_DIM + kofs);

        uint2 ap[4], bp[4];
        #pragma unroll
        for (int q = 0; q < 4; ++q) {
            ap[q] = pack4_bf16(xa[q].x, xa[q].y, xa[q].z, xa[q].w);
            bp[q] = pack4_bf16((float)wv[q].x, (float)wv[q].y,
                               (float)wv[q].z, (float)wv[q].w);
        }

        __syncthreads();
        #pragma unroll
        for (int q = 0; q < 4; ++q) {
            *(uint2*)(&As[q * 32 + srow][scol]) = ap[q];
            *(uint2*)(&Bs[q * 32 + srow][scol]) = bp[q];
        }
        __syncthreads();

        bf16x8_t af[4], bfr[4];
        #pragma unroll
        for (int m = 0; m < 4; ++m)
            af[m] = *(const bf16x8_t*)(&As[wr * 64 + m * 16 + fr][fq * 8]);
        #pragma unroll
        for (int n = 0; n < 4; ++n)
            bfr[n] = *(const bf16x8_t*)(&Bs[wc * 64 + n * 16 + fr][fq * 8]);
        #pragma unroll
        for (int m = 0; m < 4; ++m)
            #pragma unroll
            for (int n = 0; n < 4; ++n)
                acc[m][n] = __builtin_amdgcn_mfma_f32_16x16x32_bf16(
                    af[m], bfr[n], acc[m][n], 0, 0, 0);
    }

    const int n_base = tn * BN + wc * 64;
    const int m_base = tm * BM + wr * 64;
    #pragma unroll
    for (int n = 0; n < 4; ++n) {
        const int gn = n_base + n * 16 + fr;
        const float sc = Sc[gn];
        const float bi = Bi[gn];
        #pragma unroll
        for (int m = 0; m < 4; ++m) {
            const int gm0 = m_base + m * 16 + fq * 4;
            #pragma unroll
            for (int j = 0; j < 4; ++j)
                Out[(size_t)(gm0 + j) * N_DIM + gn] = acc[m][n][j] * sc + bi;
        }
    }
}

extern "C" void kernel_launch(void* const* d_in, const int* in_sizes, int n_in,
                              void* d_out, int out_size, void* d_ws, size_t ws_size,
                              hipStream_t stream) {
    const float* X  = (const float*)d_in[0];
    const int*   Wq = (const int*)d_in[1];
    const float* Sc = (const float*)d_in[2];
    const float* Bi = (const float*)d_in[3];
    float*      Out = (float*)d_out;

    const size_t nX = (size_t)M_DIM * K_DIM;     // 33,554,432
    const size_t nW = (size_t)N_DIM * K_DIM;     // 45,088,768
    const size_t ws_needed = nX + nW;            // 78.6 MB (int8)

    if (ws_size >= ws_needed) {
        char* Xq  = (char*)d_ws;
        char* Wq8 = Xq + nX;
        cvt_x_i8<<<2048, 256, 0, stream>>>(X, (uint32_t*)Xq, (int)(nX / 16));
        cvt_w_i8<<<2048, 256, 0, stream>>>(Wq, (uint32_t*)Wq8, (int)(nW / 16));
        dim3 grid2((M_DIM / BM2) * (N_DIM / BN2));   // 1376
        wq8_gemm_i8<<<grid2, 512, 0, stream>>>(Xq, Wq8, Sc, Bi, Out);
    } else {
        dim3 grid((M_DIM / BM) * (N_DIM / BN));      // 5504
        wq8_gemm_fused<<<grid, 256, 0, stream>>>(X, Wq, Sc, Bi, Out);
    }
}